// Round 3
// baseline (193.402 us; speedup 1.0000x reference)
//
#include <hip/hip_runtime.h>

#define T   512
#define B   512
#define NT  64
#define QS  16            // steps per staging quarter
#define NQ  (T / QS)      // 32 quarters
#define RING 4            // LDS ring: 4 quarters = 64 rows, lead distance 3

typedef _Float16 h2 __attribute__((ext_vector_type(2)));

__device__ __forceinline__ float rflf(float x) {
    return __uint_as_float(__builtin_amdgcn_readfirstlane(__float_as_uint(x)));
}

__device__ __forceinline__ float dot2(h2 a, h2 b, float c) {
#if __has_builtin(__builtin_amdgcn_fdot2)
    return __builtin_amdgcn_fdot2(a, b, c, false);
#else
    return c + (float)a.x * (float)b.x + (float)a.y * (float)b.y;
#endif
}

__device__ __forceinline__ h2 bch2(int u) { return __builtin_bit_cast(h2, u); }

// ---------------------------------------------------------------------------
// Fused CRF. Grid = 512 denom blocks (1 chain each, single wave) + 512
// numerator blocks.
//
// Round 3: rounds 0-2 showed ~520 cy/step with only ~160 cy of issue — the
// rest is in-order-issue stall on the serial chain. The un-hideable piece
// common to all prior versions is the PROMPT renorm (p -> readfirstlane ->
// SALU exponent -> VALU rescale): nothing independent can pad it because
// everything needs r immediately. This round:
//   - LAGGED renorm: step t applies r computed from p(t-1) (any uniform
//     power-of-2 scale is exact as long as K counts it). The rfl->SALU->VALU
//     round trip gets a full step of slack and runs in the shadow of the
//     next matvec. Step 1 is peeled with prompt renorm to seed magnitude.
//     Scale biased 2^-2 extra for f16 headroom (K += k+2).
//   - broadcast: ALL 32 readlanes batched, then sched_barrier(0), then all
//     32 dots -> every readlane->dot gap is ~64 cy (was 16).
//   - X*r multiply placed after the dot block (off the chain head); X
//     prefetched one full step ahead through a flattened 64-row LDS ring
//     (no quarter-boundary peeling: row = (s+2) & 63).
// ---------------------------------------------------------------------------
__global__ __launch_bounds__(64) void crf_fused(
    const float* __restrict__ emissions,  // [T, B, NT]
    const int*   __restrict__ tags,       // [T, B]
    const int*   __restrict__ mask,       // [T, B]
    const float* __restrict__ startT,     // [NT]
    const float* __restrict__ endT,       // [NT]
    const float* __restrict__ trans,      // [NT, NT]
    float* __restrict__ out)
{
    const int j = threadIdx.x;

    __shared__ __align__(16) float ebuf[RING][QS][NT];   // X = exp(e), 16 KB

    if (blockIdx.x < B) {
        // =============== denominator chain, b = blockIdx.x ==================
        const int b = blockIdx.x;

        // E = exp(trans) column j as f16 pairs over i (32 VGPRs)
        h2 Eh[NT / 2];
#pragma unroll
        for (int m = 0; m < NT / 2; ++m) {
            Eh[m].x = (_Float16)__expf(trans[(2 * m)     * NT + j]);
            Eh[m].y = (_Float16)__expf(trans[(2 * m + 1) * NT + j]);
        }

        // staging: lane j covers step 4k + (j>>4) of a quarter, cols (j&15)*4
        const int jr = j >> 4;
        const int c0 = (j & 15) * 4;
        float4 sA[4];

        auto issue_q = [&](int g) {
#pragma unroll
            for (int k = 0; k < 4; ++k) {
                const int t = g * QS + 4 * k + jr;
                sA[k] = *(const float4*)&emissions[((size_t)t * B + b) * NT + c0];
            }
        };
        auto write_q = [&](int g) {   // exp() applied here, off the chain
#pragma unroll
            for (int k = 0; k < 4; ++k) {
                float4 w;
                w.x = __expf(sA[k].x); w.y = __expf(sA[k].y);
                w.z = __expf(sA[k].z); w.w = __expf(sA[k].w);
                *(float4*)&ebuf[g & (RING - 1)][4 * k + jr][c0] = w;
            }
        };

        for (int g = 0; g < 3; ++g) { issue_q(g); write_q(g); }
        issue_q(3);

        // t = 0 init
        const float e0  = emissions[(size_t)b * NT + j];
        const float sc0 = startT[j] + e0;
        const float S0  = rflf(sc0);
        float q = __expf(sc0 - S0);
        int   K = 0;

        // initial f16 pair pack (even lane 2n holds (q_2n, q_2n+1))
        int pk_i;
        {
            const int qi = __float_as_int(q);
            const int qo = __builtin_amdgcn_update_dpp(0, qi, 0xB1, 0xF, 0xF, true);
            pk_i = __builtin_bit_cast(int,
                    __builtin_amdgcn_cvt_pkrtz(q, __int_as_float(qo)));
        }

        float* eflat = &ebuf[0][0][0];         // 64-row ring view
        int bits_prev;                          // rfl'd exponent source (lag)
        int mpre = mask[j * B + b];             // chunk-0 mask column
        unsigned long long mbc = 0;

        // ---- peeled step 1: prompt renorm seeds bits_prev magnitude ----
        {
            int u[32];
#pragma unroll
            for (int n = 0; n < 32; ++n)
                u[n] = __builtin_amdgcn_readlane(pk_i, 2 * n);
            float a[8] = {0.f, 0.f, 0.f, 0.f, 0.f, 0.f, 0.f, 0.f};
#pragma unroll
            for (int n = 0; n < 32; ++n)
                a[n & 7] = dot2(bch2(u[n]), Eh[n], a[n & 7]);
            const float p = ((a[0] + a[1]) + (a[2] + a[3]))
                          + ((a[4] + a[5]) + (a[6] + a[7]));
            bits_prev = __builtin_amdgcn_readfirstlane(__float_as_int(p));
            const int  k = ((bits_prev >> 23) & 255) - 127;
            const float r = __int_as_float((125 - k) << 23);   // 2^-(k+2)
            const float X1 = eflat[NT + j];
            const int  m1 = mask[B + b];
            if (m1) { q = (p * X1) * r; K = k + 2; }
            const int qo = __builtin_amdgcn_update_dpp(0, __float_as_int(q),
                                                       0xB1, 0xF, 0xF, true);
            pk_i = __builtin_bit_cast(int,
                    __builtin_amdgcn_cvt_pkrtz(q, __int_as_float(qo)));
        }

        // X pipeline for s >= 2 (one full step of prefetch distance)
        float Xc = eflat[2 * NT + j];
        float Xn = eflat[3 * NT + j];

        // ---- lagged step bodies ----
        auto stepF = [&](int s) {               // unmasked
            int u[32];
#pragma unroll
            for (int n = 0; n < 32; ++n)
                u[n] = __builtin_amdgcn_readlane(pk_i, 2 * n);
            __builtin_amdgcn_sched_barrier(0);  // readlanes stay batched here
            const int  k = ((bits_prev >> 23) & 255) - 127;   // lagged
            const float r = __int_as_float((125 - k) << 23);
            K += k + 2;
            float a[8] = {0.f, 0.f, 0.f, 0.f, 0.f, 0.f, 0.f, 0.f};
#pragma unroll
            for (int n = 0; n < 32; ++n)
                a[n & 7] = dot2(bch2(u[n]), Eh[n], a[n & 7]);
            const float sXr = Xc * r;           // off the chain head
            const float p = ((a[0] + a[1]) + (a[2] + a[3]))
                          + ((a[4] + a[5]) + (a[6] + a[7]));
            q = p * sXr;
            bits_prev = __builtin_amdgcn_readfirstlane(__float_as_int(p));
            const int qo = __builtin_amdgcn_update_dpp(0, __float_as_int(q),
                                                       0xB1, 0xF, 0xF, true);
            pk_i = __builtin_bit_cast(int,
                    __builtin_amdgcn_cvt_pkrtz(q, __int_as_float(qo)));
            Xc = Xn;
            Xn = eflat[((s + 2) & 63) * NT + j];   // ring prefetch
        };

        auto stepM = [&](int s) {               // masked variant
            int u[32];
#pragma unroll
            for (int n = 0; n < 32; ++n)
                u[n] = __builtin_amdgcn_readlane(pk_i, 2 * n);
            __builtin_amdgcn_sched_barrier(0);
            const int  k = ((bits_prev >> 23) & 255) - 127;
            const float r = __int_as_float((125 - k) << 23);
            const bool mc = (mbc >> (s & 63)) & 1ull;
            const float mf = mc ? 1.0f : 0.0f;
            K += mc ? (k + 2) : 0;
            float a[8] = {0.f, 0.f, 0.f, 0.f, 0.f, 0.f, 0.f, 0.f};
#pragma unroll
            for (int n = 0; n < 32; ++n)
                a[n & 7] = dot2(bch2(u[n]), Eh[n], a[n & 7]);
            const float sXr = Xc * r;
            const float p = ((a[0] + a[1]) + (a[2] + a[3]))
                          + ((a[4] + a[5]) + (a[6] + a[7]));
            const float qn = p * sXr;
            q = fmaf(mf, qn - q, q);            // mf=0 -> q exactly
            bits_prev = __builtin_amdgcn_readfirstlane(__float_as_int(p));
            const int qo = __builtin_amdgcn_update_dpp(0, __float_as_int(q),
                                                       0xB1, 0xF, 0xF, true);
            pk_i = __builtin_bit_cast(int,
                    __builtin_amdgcn_cvt_pkrtz(q, __int_as_float(qo)));
            Xc = Xn;
            Xn = eflat[((s + 2) & 63) * NT + j];
        };

        for (int x = 0; x < NQ; ++x) {
            const int gw = (x + 3 < NQ) ? x + 3 : NQ - 1;
            write_q(gw);
            const int gl = (x + 4 < NQ) ? x + 4 : NQ - 1;
            issue_q(gl);

            if ((x & 3) == 0) {                // 64-step chunk boundary
                mbc = __ballot(mpre != 0);
                const int cn = ((x >> 2) + 1 < 8) ? (x >> 2) + 1 : 7;
                mpre = mask[(cn * 64 + j) * B + b];
            }

            const unsigned qb = (unsigned)(mbc >> ((x & 3) << 4)) & 0xFFFFu;
            const int tt0 = (x == 0) ? 2 : 0;   // steps 0,1 handled above

            if (qb == 0xFFFFu) {
#pragma unroll 1
                for (int tt = tt0; tt < QS; ++tt) stepF(x * QS + tt);
            } else {
#pragma unroll 1
                for (int tt = tt0; tt < QS; ++tt) stepM(x * QS + tt);
            }
        }

        // den_b = S0 + K*ln2 + log( sum_j q_j * exp(endT_j) )
        float v = q * __expf(endT[j]);
#pragma unroll
        for (int off = 32; off > 0; off >>= 1)
            v += __shfl_xor(v, off);
        if (j == 0)
            atomicAdd(out, -(S0 + (float)K * 0.69314718f + __logf(v)));

    } else {
        // =============== numerator wave, b = blockIdx.x - B =================
        const int b = blockIdx.x - B;

        float acc = 0.f;
        int   cnt = 0;
#pragma unroll
        for (int m = 0; m < T / 64; ++m) {
            const int t  = j + 64 * m;
            const int mv = mask[t * B + b];
            const int tg = tags[t * B + b];
            cnt += (int)__popcll(__ballot(mv != 0));
            if (t == 0) {
                acc += startT[tg] + emissions[(size_t)b * NT + tg];
            } else if (mv) {
                const int tp = tags[(t - 1) * B + b];
                acc += trans[tp * NT + tg]
                     + emissions[(size_t)(t * B + b) * NT + tg];
            }
        }
#pragma unroll
        for (int off = 32; off > 0; off >>= 1)
            acc += __shfl_xor(acc, off);
        if (j == 0) {
            const int last = tags[(size_t)(cnt - 1) * B + b];
            atomicAdd(out, acc + endT[last]);
        }
    }
}

extern "C" void kernel_launch(void* const* d_in, const int* in_sizes, int n_in,
                              void* d_out, int out_size, void* d_ws, size_t ws_size,
                              hipStream_t stream) {
    const float* emissions = (const float*)d_in[0];
    const int*   tags      = (const int*)  d_in[1];
    const int*   mask      = (const int*)  d_in[2];
    const float* startT    = (const float*)d_in[3];
    const float* endT      = (const float*)d_in[4];
    const float* trans     = (const float*)d_in[5];
    float* out = (float*)d_out;

    hipMemsetAsync(out, 0, sizeof(float), stream);
    crf_fused<<<2 * B, 64, 0, stream>>>(
        emissions, tags, mask, startT, endT, trans, out);
}